// Round 3
// baseline (681.470 us; speedup 1.0000x reference)
//
#include <hip/hip_runtime.h>
#include <hip/hip_bf16.h>

#define NN 50000
#define NE 800000

typedef __attribute__((ext_vector_type(8))) short short8;
typedef __attribute__((ext_vector_type(4))) float f32x4;

static __device__ __forceinline__ short f2bf(float f) {
    __hip_bfloat16 h = __float2bfloat16(f);   // RNE
    return __builtin_bit_cast(short, h);
}

static __device__ __forceinline__ short8 cvt8(f32x4 a, f32x4 b) {
    short8 v;
    v[0] = f2bf(a[0]); v[1] = f2bf(a[1]); v[2] = f2bf(a[2]); v[3] = f2bf(a[3]);
    v[4] = f2bf(b[0]); v[5] = f2bf(b[1]); v[6] = f2bf(b[2]); v[7] = f2bf(b[3]);
    return v;
}

// Load B fragments for a [K][64] fp32 weight matrix into per-lane registers.
// Slot map: frag[t][nt][i] = W[(32t + 8g + i)][16nt + er]  (consistent A/B bijection)
#define LOAD_BFRAGS(W, FR, KT)                                        \
    _Pragma("unroll")                                                 \
    for (int t = 0; t < (KT); ++t) {                                  \
        _Pragma("unroll")                                             \
        for (int nt = 0; nt < 4; ++nt) {                              \
            short8 v;                                                 \
            _Pragma("unroll")                                         \
            for (int i = 0; i < 8; ++i)                               \
                v[i] = f2bf((W)[(32*t + 8*g + i)*64 + 16*nt + er]);   \
            FR[t][nt] = v;                                            \
        }                                                             \
    }

// ---------- CSR build ----------
__global__ void hist_kernel(const int* __restrict__ ei, int* __restrict__ cnt) {
    int e = blockIdx.x * 256 + threadIdx.x;
    if (e < NE) atomicAdd(&cnt[ei[e]], 1);
}

__global__ void scan_kernel(const int* __restrict__ cnt,
                            int* __restrict__ off, int* __restrict__ cursor) {
    __shared__ int sums[256];
    const int t = threadIdx.x;
    const int base = t * 196;                 // 256*196 = 50176 >= NN
    int s = 0;
    for (int i = 0; i < 196; ++i) { int idx = base + i; if (idx < NN) s += cnt[idx]; }
    sums[t] = s; __syncthreads();
    for (int d = 1; d < 256; d <<= 1) {
        int u = (t >= d) ? sums[t - d] : 0;
        __syncthreads();
        sums[t] += u;
        __syncthreads();
    }
    int run = sums[t] - s;                    // exclusive prefix for this chunk
    for (int i = 0; i < 196; ++i) {
        int idx = base + i;
        if (idx < NN) { off[idx] = run; cursor[idx] = run; run += cnt[idx]; }
    }
    if (t == 255) off[NN] = run;
}

__global__ void fill_kernel(const int* __restrict__ ei,
                            int* __restrict__ cursor, int* __restrict__ elist) {
    int e = blockIdx.x * 256 + threadIdx.x;
    if (e < NE) { int p = atomicAdd(&cursor[ei[e]], 1); elist[p] = e; }
}

// ---------- per-node edge MLP + mean-aggregate (no value atomics) ----------
__global__ __launch_bounds__(256, 2) void edge_agg_kernel(
    const float* __restrict__ x, const int* __restrict__ ei,
    const float* __restrict__ ea,
    const int* __restrict__ off, const int* __restrict__ elist,
    const float* __restrict__ W1a, const float* __restrict__ b1a,
    const float* __restrict__ W1b, const float* __restrict__ b1b,
    float* __restrict__ agg /* = d_out, overwritten later by node_kernel */)
{
    __shared__ short h1s[4][16*64];          // per-wave transpose buffer (XOR-swizzled)
    const int tid  = threadIdx.x;
    const int wid  = tid >> 6;
    const int lane = tid & 63;
    const int er   = lane & 15;              // edge slot (A row / C col index)
    const int g    = lane >> 4;
    short* myh1 = h1s[wid];

    short8 Wa[4][4];                         // layer1 weights, K=128
    short8 Wb[2][4];                         // layer2 weights, K=64
    LOAD_BFRAGS(W1a, Wa, 4)
    LOAD_BFRAGS(W1b, Wb, 2)
    float bias1[4], bias2[4];
    #pragma unroll
    for (int nt = 0; nt < 4; ++nt) { bias1[nt] = b1a[16*nt + er]; bias2[nt] = b1b[16*nt + er]; }

    for (int n = blockIdx.x * 4 + wid; n < NN; n += gridDim.x * 4) {
        const int o0  = off[n];
        const int deg = off[n + 1] - o0;
        float psum[4] = {0.f, 0.f, 0.f, 0.f};

        for (int c0 = 0; c0 < deg; c0 += 16) {
            // edge id for this lane's A-row slot (clamped; masked at reduce)
            const int eid = elist[(c0 + er < deg) ? (o0 + c0 + er) : o0];
            const int col = ei[NE + eid];
            const float* xr = x  + (size_t)col * 64;
            const float* qr = ea + (size_t)eid * 64;

            // A fragments: in[e] = [x[col[e]] | ea[e]], k = 32t + 8g + i
            short8 A[4];
            #pragma unroll
            for (int t = 0; t < 2; ++t) {
                f32x4 v0 = *(const f32x4*)(xr + 32*t + 8*g);
                f32x4 v1 = *(const f32x4*)(xr + 32*t + 8*g + 4);
                A[t] = cvt8(v0, v1);
            }
            #pragma unroll
            for (int t = 0; t < 2; ++t) {
                f32x4 v0 = *(const f32x4*)(qr + 32*t + 8*g);
                f32x4 v1 = *(const f32x4*)(qr + 32*t + 8*g + 4);
                A[2+t] = cvt8(v0, v1);
            }

            f32x4 acc[4] = {{0,0,0,0},{0,0,0,0},{0,0,0,0},{0,0,0,0}};
            #pragma unroll
            for (int t = 0; t < 4; ++t)
                #pragma unroll
                for (int nt = 0; nt < 4; ++nt)
                    acc[nt] = __builtin_amdgcn_mfma_f32_16x16x32_bf16(A[t], Wa[t][nt], acc[nt], 0, 0, 0);

            // h1 = relu(acc + b1a); write transposed (edge-major) into LDS, XOR swizzle
            #pragma unroll
            for (int r = 0; r < 4; ++r) {
                const int e = 4*g + r;                    // C row = edge slot
                const int swz = (e & 7) << 3;
                #pragma unroll
                for (int nt = 0; nt < 4; ++nt) {
                    float h = acc[nt][r] + bias1[nt];
                    h = h > 0.0f ? h : 0.0f;
                    myh1[e*64 + ((16*nt + er) ^ swz)] = f2bf(h);
                }
            }

            // layer 2: A2[e][k2], k2 = 32t + 8g + i, read back swizzled
            const int swr = (er & 7) << 3;
            short8 A2[2];
            #pragma unroll
            for (int t = 0; t < 2; ++t)
                A2[t] = *(const short8*)(myh1 + er*64 + ((32*t + 8*g) ^ swr));

            f32x4 acc2[4] = {{0,0,0,0},{0,0,0,0},{0,0,0,0},{0,0,0,0}};
            #pragma unroll
            for (int t = 0; t < 2; ++t)
                #pragma unroll
                for (int nt = 0; nt < 4; ++nt)
                    acc2[nt] = __builtin_amdgcn_mfma_f32_16x16x32_bf16(A2[t], Wb[t][nt], acc2[nt], 0, 0, 0);

            // masked row-accumulate (sum over this chunk's valid edges)
            #pragma unroll
            for (int r = 0; r < 4; ++r) {
                const bool valid = (c0 + 4*g + r) < deg;
                #pragma unroll
                for (int nt = 0; nt < 4; ++nt)
                    psum[nt] += valid ? (acc2[nt][r] + bias2[nt]) : 0.0f;
            }
        }

        // reduce across the 4 row-groups (lanes er, er+16, er+32, er+48)
        #pragma unroll
        for (int nt = 0; nt < 4; ++nt) {
            psum[nt] += __shfl_xor(psum[nt], 16);
            psum[nt] += __shfl_xor(psum[nt], 32);
        }
        // lane l = 16g + er stores feature l  (static select, no scratch)
        float sel = (g == 0) ? psum[0] : (g == 1) ? psum[1] : (g == 2) ? psum[2] : psum[3];
        const float rdeg = 1.0f / fmaxf((float)deg, 1.0f);
        agg[(size_t)n * 64 + lane] = sel * rdeg;
    }
}

// ---------- per-node MLP2 (reads agg from d_out rows, overwrites in place) ----------
__global__ __launch_bounds__(256, 2) void node_kernel(
    const float* __restrict__ x,
    const float* __restrict__ W2a, const float* __restrict__ b2a,
    const float* __restrict__ W2b, const float* __restrict__ b2b,
    float* out /* in: agg rows, out: final output (same rows, same wave) */)
{
    __shared__ short h1s[4][16*64];
    const int tid  = threadIdx.x;
    const int wid  = tid >> 6;
    const int lane = tid & 63;
    const int er   = lane & 15;
    const int g    = lane >> 4;
    short* myh1 = h1s[wid];

    short8 Wa[4][4];
    short8 Wb[2][4];
    LOAD_BFRAGS(W2a, Wa, 4)
    LOAD_BFRAGS(W2b, Wb, 2)
    float bias1[4], bias2[4];
    #pragma unroll
    for (int nt = 0; nt < 4; ++nt) { bias1[nt] = b2a[16*nt + er]; bias2[nt] = b2b[16*nt + er]; }

    const int tile = blockIdx.x * 4 + wid;
    if (tile >= (NN + 15) / 16) return;
    const int nb   = tile * 16;
    const int node = min(nb + er, NN - 1);    // clamp for the 50000%16==0 case (exact here)

    const float* xr = x   + (size_t)node * 64;
    const float* sr = out + (size_t)node * 64;            // agg row

    short8 A[4];
    #pragma unroll
    for (int t = 0; t < 2; ++t) {
        f32x4 v0 = *(const f32x4*)(xr + 32*t + 8*g);
        f32x4 v1 = *(const f32x4*)(xr + 32*t + 8*g + 4);
        A[t] = cvt8(v0, v1);
    }
    #pragma unroll
    for (int t = 0; t < 2; ++t) {
        f32x4 v0 = *(const f32x4*)(sr + 32*t + 8*g);
        f32x4 v1 = *(const f32x4*)(sr + 32*t + 8*g + 4);
        A[2+t] = cvt8(v0, v1);
    }

    f32x4 acc[4] = {{0,0,0,0},{0,0,0,0},{0,0,0,0},{0,0,0,0}};
    #pragma unroll
    for (int t = 0; t < 4; ++t)
        #pragma unroll
        for (int nt = 0; nt < 4; ++nt)
            acc[nt] = __builtin_amdgcn_mfma_f32_16x16x32_bf16(A[t], Wa[t][nt], acc[nt], 0, 0, 0);

    #pragma unroll
    for (int r = 0; r < 4; ++r) {
        const int e = 4*g + r;
        const int swz = (e & 7) << 3;
        #pragma unroll
        for (int nt = 0; nt < 4; ++nt) {
            float h = acc[nt][r] + bias1[nt];
            h = h > 0.0f ? h : 0.0f;
            myh1[e*64 + ((16*nt + er) ^ swz)] = f2bf(h);
        }
    }

    const int swr = (er & 7) << 3;
    short8 A2[2];
    #pragma unroll
    for (int t = 0; t < 2; ++t)
        A2[t] = *(const short8*)(myh1 + er*64 + ((32*t + 8*g) ^ swr));

    f32x4 acc2[4] = {{0,0,0,0},{0,0,0,0},{0,0,0,0},{0,0,0,0}};
    #pragma unroll
    for (int t = 0; t < 2; ++t)
        #pragma unroll
        for (int nt = 0; nt < 4; ++nt)
            acc2[nt] = __builtin_amdgcn_mfma_f32_16x16x32_bf16(A2[t], Wb[t][nt], acc2[nt], 0, 0, 0);

    // all reads of this tile's rows happened above (same wave) — safe to overwrite
    #pragma unroll
    for (int r = 0; r < 4; ++r) {
        float* orow = out + (size_t)(nb + 4*g + r) * 64 + er;
        #pragma unroll
        for (int nt = 0; nt < 4; ++nt)
            orow[16*nt] = acc2[nt][r] + bias2[nt];
    }
}

extern "C" void kernel_launch(void* const* d_in, const int* in_sizes, int n_in,
                              void* d_out, int out_size, void* d_ws, size_t ws_size,
                              hipStream_t stream)
{
    const float* x   = (const float*)d_in[0];
    const int*   ei  = (const int*)d_in[1];
    const float* ea  = (const float*)d_in[2];
    // d_in[3] = u (unused), d_in[4] = batch (unused)
    const float* W1a = (const float*)d_in[5];
    const float* b1a = (const float*)d_in[6];
    const float* W1b = (const float*)d_in[7];
    const float* b1b = (const float*)d_in[8];
    const float* W2a = (const float*)d_in[9];
    const float* b2a = (const float*)d_in[10];
    const float* W2b = (const float*)d_in[11];
    const float* b2b = (const float*)d_in[12];

    float* out = (float*)d_out;

    // ws layout: cnt[NN] | off[NN+1] | cursor[NN] | elist[NE]   (~3.8 MB)
    int* cnt    = (int*)d_ws;
    int* off    = cnt + NN;
    int* cursor = off + NN + 1;
    int* elist  = cursor + NN;

    hipMemsetAsync(cnt, 0, (size_t)NN * sizeof(int), stream);

    hist_kernel<<<(NE + 255) / 256, 256, 0, stream>>>(ei, cnt);
    scan_kernel<<<1, 256, 0, stream>>>(cnt, off, cursor);
    fill_kernel<<<(NE + 255) / 256, 256, 0, stream>>>(ei, cursor, elist);

    // one wave per node, 4 nodes per wave via grid-stride
    edge_agg_kernel<<<3125, 256, 0, stream>>>(x, ei, ea, off, elist,
                                              W1a, b1a, W1b, b1b, out);
    node_kernel<<<782, 256, 0, stream>>>(x, W2a, b2a, W2b, b2b, out);
}